// Round 1
// baseline (6019.418 us; speedup 1.0000x reference)
//
#include <hip/hip_runtime.h>
#include <stdint.h>

// ---------------- workspace layout (bytes) ----------------
#define WS_TABLE0   0           // 128*1536*4 = 786432
#define WS_WHH0B    786432      // 1536*512*2
#define WS_WIH1B    2359296
#define WS_WHH1B    3932160
#define WS_WD1B     5505024     // 1024*512*2
#define WS_WD2B     6553600     // 512*1024*2
#define WS_WM       7602176     // 12*512*4
#define WS_BM       7626752     // 12*4 (padded)
#define WS_H0B      7627008     // 2*256*512*2
#define WS_H1B      8151296     // 2*256*512*2
#define WS_Y1       8675584     // 256*1024*4
#define WS_X1B      9724160     // 256*1024*2
#define WS_Y2       10248448    // 256*512*4
#define WS_X2B      10772736    // 256*512*2
#define WS_BAR      11034880    // 16 * 256B barrier slots

typedef __attribute__((ext_vector_type(8))) short bf16x8;
typedef __attribute__((ext_vector_type(4))) float f32x4;

__device__ __forceinline__ unsigned short f2bf(float f) {
  uint32_t u = __builtin_bit_cast(uint32_t, f);
  u += 0x7fffu + ((u >> 16) & 1u);
  return (unsigned short)(u >> 16);
}
__device__ __forceinline__ float bf2f(unsigned short s) {
  uint32_t u = ((uint32_t)s) << 16;
  return __builtin_bit_cast(float, u);
}
__device__ __forceinline__ float sigf(float x) { return 1.f / (1.f + __expf(-x)); }
__device__ __forceinline__ float tanhs(float x) {
  x = fminf(fmaxf(x, -10.f), 10.f);
  float e = __expf(2.f * x);
  return (e - 1.f) / (e + 1.f);
}

// device-scope sense-reversing barrier: bar[0]=count, bar[1]=generation
__device__ __forceinline__ void gbar(int* bar, int expected) {
  __syncthreads();
  if (threadIdx.x == 0) {
    __threadfence();  // release: publish prior stores device-wide
    int g0 = __hip_atomic_load(bar + 1, __ATOMIC_RELAXED, __HIP_MEMORY_SCOPE_AGENT);
    int a = __hip_atomic_fetch_add(bar, 1, __ATOMIC_ACQ_REL, __HIP_MEMORY_SCOPE_AGENT);
    if (a == expected - 1) {
      __hip_atomic_store(bar, 0, __ATOMIC_RELAXED, __HIP_MEMORY_SCOPE_AGENT);
      __hip_atomic_fetch_add(bar + 1, 1, __ATOMIC_RELEASE, __HIP_MEMORY_SCOPE_AGENT);
    } else {
      while (__hip_atomic_load(bar + 1, __ATOMIC_RELAXED, __HIP_MEMORY_SCOPE_AGENT) == g0) {
        __builtin_amdgcn_s_sleep(1);
      }
    }
    __threadfence();  // acquire: invalidate stale cached lines
  }
  __syncthreads();
}

// ---------------- prep kernels ----------------
__global__ void k_zero(uint4* p, int n16) {
  int i = blockIdx.x * 256 + threadIdx.x;
  if (i < n16) p[i] = make_uint4(0u, 0u, 0u, 0u);
}

__global__ void k_cvt(const float* __restrict__ src, unsigned short* __restrict__ dst, int n) {
  int i = (blockIdx.x * 256 + threadIdx.x) * 4;
  if (i < n) {
    float4 v = *(const float4*)(src + i);
    dst[i + 0] = f2bf(v.x);
    dst[i + 1] = f2bf(v.y);
    dst[i + 2] = f2bf(v.z);
    dst[i + 3] = f2bf(v.w);
  }
}

// table0[v][c] = sum_k emb[v][k] * W_ih0[c][k] + b_ih0[c]
__global__ void k_table(const float* __restrict__ emb, const float* __restrict__ Wih0,
                        const float* __restrict__ bih0, float* __restrict__ table) {
  __shared__ float e[512];
  int v = blockIdx.x;
  for (int i = threadIdx.x; i < 512; i += 256) e[i] = emb[v * 512 + i];
  __syncthreads();
  for (int cidx = threadIdx.x; cidx < 1536; cidx += 256) {
    const float* w = Wih0 + (size_t)cidx * 512;
    float s = 0.f;
    #pragma unroll 4
    for (int k = 0; k < 512; k += 4) {
      float4 w4 = *(const float4*)(w + k);
      s += w4.x * e[k] + w4.y * e[k + 1] + w4.z * e[k + 2] + w4.w * e[k + 3];
    }
    table[(size_t)v * 1536 + cidx] = s + bih0[cidx];
  }
}

// Wm[t][d] = mean_e We[e][t][d] ; bm[t] = mean_e be[e][t]
__global__ void k_wm(const float* __restrict__ We, const float* __restrict__ be,
                     float* __restrict__ Wm, float* __restrict__ bm) {
  int i = blockIdx.x * 256 + threadIdx.x;
  if (i < 12 * 512) {
    int t = i / 512, d = i % 512;
    float s = 0.f;
    for (int e = 0; e < 5; ++e) s += We[((size_t)e * 12 + t) * 512 + d];
    Wm[i] = s * 0.2f;
  }
  if (i < 12) {
    float s = 0.f;
    for (int e = 0; e < 5; ++e) s += be[e * 12 + i];
    bm[i] = s * 0.2f;
  }
}

// ---------------- persistent main kernel ----------------
// 256 WGs x 256 threads. group = bid&7 (32 WGs), owns batch rows [32g,32g+32).
// member = bid>>3 owns h-cols [16*member, +16).
// LDS: [0,147456) = 3 weight slices (48 rows x 512 bf16 each, XOR-swizzled)
//      [147456, 156160) = 8 acc frags x 16x17 f32 reduction scratch
__global__ void __launch_bounds__(256, 1) k_main(
    const int* __restrict__ smiles,
    const float* __restrict__ bhh0,
    const float* __restrict__ bih1,
    const float* __restrict__ bhh1,
    const float* __restrict__ bd1,
    const float* __restrict__ gam1,
    const float* __restrict__ bet1,
    const float* __restrict__ bd2,
    const float* __restrict__ gam2,
    const float* __restrict__ bet2,
    char* __restrict__ ws,
    float* __restrict__ out) {
  extern __shared__ char lds[];
  const int tid = threadIdx.x, bid = blockIdx.x;
  const int lane = tid & 63, wave = tid >> 6;
  const int grp = bid & 7, member = bid >> 3;
  const int hc = member * 16;
  const int l15 = lane & 15, l4 = lane >> 4;

  const float* table0 = (const float*)(ws + WS_TABLE0);
  const unsigned short* Whh0b = (const unsigned short*)(ws + WS_WHH0B);
  const unsigned short* Wih1b = (const unsigned short*)(ws + WS_WIH1B);
  const unsigned short* Whh1b = (const unsigned short*)(ws + WS_WHH1B);
  const unsigned short* Wd1b = (const unsigned short*)(ws + WS_WD1B);
  const unsigned short* Wd2b = (const unsigned short*)(ws + WS_WD2B);
  const float* Wm = (const float*)(ws + WS_WM);
  const float* bm = (const float*)(ws + WS_BM);
  unsigned short* h0b = (unsigned short*)(ws + WS_H0B);
  unsigned short* h1b = (unsigned short*)(ws + WS_H1B);
  float* Y1 = (float*)(ws + WS_Y1);
  unsigned short* X1b = (unsigned short*)(ws + WS_X1B);
  float* Y2 = (float*)(ws + WS_Y2);
  unsigned short* X2b = (unsigned short*)(ws + WS_X2B);
  int* barg = (int*)(ws + WS_BAR + grp * 256);
  int* barall = (int*)(ws + WS_BAR + 8 * 256);

  float* accS = (float*)(lds + 147456);

  // ---- stage weight slices into LDS (XOR-swizzled at 16B granularity) ----
  for (int u = tid; u < 3 * 48 * 64; u += 256) {
    int mat = u / (48 * 64);
    int rem = u - mat * (48 * 64);
    int r = rem >> 6, c16 = rem & 63;
    const unsigned short* src = (mat == 0) ? Whh0b : (mat == 1) ? Wih1b : Whh1b;
    int grow = (r >> 4) * 512 + hc + (r & 15);
    uint4 v = *(const uint4*)(src + (size_t)grow * 512 + c16 * 8);
    int off = mat * 49152 + r * 1024 + ((c16 * 16) ^ ((r & 7) << 4));
    *(uint4*)(lds + off) = v;
  }
  __syncthreads();

  const int c = hc + l15;  // this lane's h/gate column
  const float bh0r = bhh0[c], bh0z = bhh0[512 + c], bh0n = bhh0[1024 + c];
  const float b1r = bih1[c] + bhh1[c];
  const float b1z = bih1[512 + c] + bhh1[512 + c];
  const float b1xn = bih1[1024 + c];
  const float b1hn = bhh1[1024 + c];
  const int swz = (l15 & 7) << 4;

  auto ldsB = [&](int mat, int gate, int kc) -> bf16x8 {
    int off = mat * 49152 + (gate * 16 + l15) * 1024 + ((((kc << 6) + (l4 << 4))) ^ swz);
    return *(const bf16x8*)(lds + off);
  };
  auto loadA = [&](const unsigned short* base, int kc) -> bf16x8 {
    return *(const bf16x8*)(base + (size_t)l15 * 512 + (kc << 5) + (l4 << 3));
  };

  float h0m[8], h1m[4];
  #pragma unroll
  for (int i = 0; i < 8; ++i) h0m[i] = 0.f;
  #pragma unroll
  for (int i = 0; i < 4; ++i) h1m[i] = 0.f;

  const int rowbase = grp * 32;
  const f32x4 z4 = {0.f, 0.f, 0.f, 0.f};

  // pipelined recurrence: step s computes L0(s) on wave0, L1(s-1) on waves1-3 (K-split)
  for (int s = 0; s <= 256; ++s) {
    const unsigned short* h0rd = h0b + (size_t)((s + 1) & 1) * 131072 + (size_t)rowbase * 512;
    const unsigned short* h1rd = h1b + (size_t)(s & 1) * 131072 + (size_t)rowbase * 512;

    f32x4 pr[2], pz[2], pxn[2], phn[2];
    pr[0] = z4; pr[1] = z4; pz[0] = z4; pz[1] = z4;
    pxn[0] = z4; pxn[1] = z4; phn[0] = z4; phn[1] = z4;

    if (wave == 0) {
      if (s < 256) {
        // prefetch xi0 gathers (independent of GEMM)
        float xg[2][4][3];
        #pragma unroll
        for (int mt = 0; mt < 2; ++mt) {
          #pragma unroll
          for (int q = 0; q < 4; ++q) {
            int b = rowbase + mt * 16 + 4 * l4 + q;
            int tok = smiles[(size_t)b * 256 + s];
            const float* tb = table0 + (size_t)tok * 1536 + c;
            xg[mt][q][0] = tb[0];
            xg[mt][q][1] = tb[512];
            xg[mt][q][2] = tb[1024];
          }
        }
        f32x4 acc[3][2];
        #pragma unroll
        for (int gi = 0; gi < 3; ++gi) { acc[gi][0] = z4; acc[gi][1] = z4; }
        #pragma unroll 4
        for (int kc = 0; kc < 16; ++kc) {
          bf16x8 a0 = loadA(h0rd, kc);
          bf16x8 a1 = loadA(h0rd + 16 * 512, kc);
          #pragma unroll
          for (int gi = 0; gi < 3; ++gi) {
            bf16x8 bb = ldsB(0, gi, kc);
            acc[gi][0] = __builtin_amdgcn_mfma_f32_16x16x32_bf16(a0, bb, acc[gi][0], 0, 0, 0);
            acc[gi][1] = __builtin_amdgcn_mfma_f32_16x16x32_bf16(a1, bb, acc[gi][1], 0, 0, 0);
          }
        }
        unsigned short* h0wr = h0b + (size_t)(s & 1) * 131072;
        #pragma unroll
        for (int mt = 0; mt < 2; ++mt) {
          #pragma unroll
          for (int q = 0; q < 4; ++q) {
            int b = rowbase + mt * 16 + 4 * l4 + q;
            float rr = sigf(xg[mt][q][0] + acc[0][mt][q] + bh0r);
            float zz = sigf(xg[mt][q][1] + acc[1][mt][q] + bh0z);
            float nn = tanhs(xg[mt][q][2] + rr * (acc[2][mt][q] + bh0n));
            float hv = (1.f - zz) * nn + zz * h0m[mt * 4 + q];
            h0m[mt * 4 + q] = hv;
            h0wr[(size_t)b * 512 + c] = f2bf(hv);
          }
        }
      }
    } else {
      if (s >= 1) {
        const int wi = wave - 1;
        const int kc0 = (wi == 0) ? 0 : (wi == 1) ? 6 : 11;
        const int kc1 = (wi == 0) ? 6 : (wi == 1) ? 11 : 16;
        #pragma unroll 2
        for (int kc = kc0; kc < kc1; ++kc) {
          bf16x8 x0 = loadA(h0rd, kc);
          bf16x8 x1 = loadA(h0rd + 16 * 512, kc);
          bf16x8 y0 = loadA(h1rd, kc);
          bf16x8 y1 = loadA(h1rd + 16 * 512, kc);
          bf16x8 bxr = ldsB(1, 0, kc), bxz = ldsB(1, 1, kc), bxn = ldsB(1, 2, kc);
          bf16x8 bhr = ldsB(2, 0, kc), bhz = ldsB(2, 1, kc), bhn = ldsB(2, 2, kc);
          pr[0] = __builtin_amdgcn_mfma_f32_16x16x32_bf16(x0, bxr, pr[0], 0, 0, 0);
          pr[0] = __builtin_amdgcn_mfma_f32_16x16x32_bf16(y0, bhr, pr[0], 0, 0, 0);
          pr[1] = __builtin_amdgcn_mfma_f32_16x16x32_bf16(x1, bxr, pr[1], 0, 0, 0);
          pr[1] = __builtin_amdgcn_mfma_f32_16x16x32_bf16(y1, bhr, pr[1], 0, 0, 0);
          pz[0] = __builtin_amdgcn_mfma_f32_16x16x32_bf16(x0, bxz, pz[0], 0, 0, 0);
          pz[0] = __builtin_amdgcn_mfma_f32_16x16x32_bf16(y0, bhz, pz[0], 0, 0, 0);
          pz[1] = __builtin_amdgcn_mfma_f32_16x16x32_bf16(x1, bxz, pz[1], 0, 0, 0);
          pz[1] = __builtin_amdgcn_mfma_f32_16x16x32_bf16(y1, bhz, pz[1], 0, 0, 0);
          pxn[0] = __builtin_amdgcn_mfma_f32_16x16x32_bf16(x0, bxn, pxn[0], 0, 0, 0);
          pxn[1] = __builtin_amdgcn_mfma_f32_16x16x32_bf16(x1, bxn, pxn[1], 0, 0, 0);
          phn[0] = __builtin_amdgcn_mfma_f32_16x16x32_bf16(y0, bhn, phn[0], 0, 0, 0);
          phn[1] = __builtin_amdgcn_mfma_f32_16x16x32_bf16(y1, bhn, phn[1], 0, 0, 0);
        }
      }
    }

    // cross-wave K-reduction of L1 partials (3 rounds, LDS f32, stride-17 pad)
    #pragma unroll
    for (int r = 0; r < 3; ++r) {
      __syncthreads();
      if (wave >= 1 && s >= 1) {
        const int wi = wave - 1;
        #pragma unroll
        for (int j = 0; j < 8; ++j) {
          if (j % 3 == (wi + r) % 3) {
            const int gk = j >> 1, mt = j & 1;
            f32x4 v = (gk == 0) ? pr[mt] : (gk == 1) ? pz[mt] : (gk == 2) ? pxn[mt] : phn[mt];
            float* dstp = accS + j * 272;
            #pragma unroll
            for (int q = 0; q < 4; ++q) {
              int idx = (4 * l4 + q) * 17 + l15;
              if (r == 0) dstp[idx] = v[q];
              else dstp[idx] += v[q];
            }
          }
        }
      }
    }
    __syncthreads();
    if ((wave == 1 || wave == 2) && s >= 1) {
      const int mt = wave - 1;
      unsigned short* h1wr = h1b + (size_t)((s + 1) & 1) * 131072;
      #pragma unroll
      for (int q = 0; q < 4; ++q) {
        int idx = (4 * l4 + q) * 17 + l15;
        float rr = sigf(accS[(0 * 2 + mt) * 272 + idx] + b1r);
        float zz = sigf(accS[(1 * 2 + mt) * 272 + idx] + b1z);
        float nn = tanhs(accS[(2 * 2 + mt) * 272 + idx] + b1xn +
                         rr * (accS[(3 * 2 + mt) * 272 + idx] + b1hn));
        float hv = (1.f - zz) * nn + zz * h1m[q];
        h1m[q] = hv;
        int b = rowbase + mt * 16 + 4 * l4 + q;
        h1wr[(size_t)b * 512 + c] = f2bf(hv);
      }
    }
    gbar(barg, 32);
  }

  // ================= dense head =================
  gbar(barall, 256);

  // D1: Y1[256,1024] = h1 @ Wd1^T + bd1 ; tile [16 rows, 64 cols], wave owns 16 cols
  {
    const int mi = bid & 15, ni = bid >> 4;
    const unsigned short* A = h1b + 131072 + (size_t)(16 * mi) * 512;
    const int colb = 64 * ni + 16 * wave;
    f32x4 acc = z4;
    #pragma unroll 4
    for (int kc = 0; kc < 16; ++kc) {
      bf16x8 a = loadA(A, kc);
      bf16x8 bb = *(const bf16x8*)(Wd1b + (size_t)(colb + l15) * 512 + (kc << 5) + (l4 << 3));
      acc = __builtin_amdgcn_mfma_f32_16x16x32_bf16(a, bb, acc, 0, 0, 0);
    }
    #pragma unroll
    for (int q = 0; q < 4; ++q) {
      int row = 16 * mi + 4 * l4 + q, col = colb + l15;
      Y1[(size_t)row * 1024 + col] = acc[q] + bd1[col];
    }
  }
  gbar(barall, 256);

  // BN1 + ReLU -> X1b
  {
    float* red = (float*)lds;
    for (int cc = 0; cc < 4; ++cc) {
      int col = bid * 4 + cc;
      float x = Y1[(size_t)tid * 1024 + col];
      red[tid] = x; __syncthreads();
      for (int st = 128; st > 0; st >>= 1) { if (tid < st) red[tid] += red[tid + st]; __syncthreads(); }
      float mean = red[0] * (1.f / 256.f); __syncthreads();
      float d = x - mean;
      red[tid] = d * d; __syncthreads();
      for (int st = 128; st > 0; st >>= 1) { if (tid < st) red[tid] += red[tid + st]; __syncthreads(); }
      float var = red[0] * (1.f / 256.f); __syncthreads();
      float xn = gam1[col] * d * rsqrtf(var + 1e-5f) + bet1[col];
      X1b[(size_t)tid * 1024 + col] = f2bf(fmaxf(xn, 0.f));
    }
  }
  gbar(barall, 256);

  // D2: Y2[256,512] = X1 @ Wd2^T + bd2 ; tile [16,32], waves 0-1 own 16 cols each
  {
    const int mi = bid & 15, ni = bid >> 4;
    if (wave < 2) {
      const unsigned short* A = X1b + (size_t)(16 * mi) * 1024;
      const int colb = 32 * ni + 16 * wave;
      f32x4 acc = z4;
      #pragma unroll 4
      for (int kc = 0; kc < 32; ++kc) {
        bf16x8 a = *(const bf16x8*)(A + (size_t)l15 * 1024 + (kc << 5) + (l4 << 3));
        bf16x8 bb = *(const bf16x8*)(Wd2b + (size_t)(colb + l15) * 1024 + (kc << 5) + (l4 << 3));
        acc = __builtin_amdgcn_mfma_f32_16x16x32_bf16(a, bb, acc, 0, 0, 0);
      }
      #pragma unroll
      for (int q = 0; q < 4; ++q) {
        int row = 16 * mi + 4 * l4 + q, col = colb + l15;
        Y2[(size_t)row * 512 + col] = acc[q] + bd2[col];
      }
    }
  }
  gbar(barall, 256);

  // BN2 + ReLU -> X2b
  {
    float* red = (float*)lds;
    for (int cc = 0; cc < 2; ++cc) {
      int col = bid * 2 + cc;
      float x = Y2[(size_t)tid * 512 + col];
      red[tid] = x; __syncthreads();
      for (int st = 128; st > 0; st >>= 1) { if (tid < st) red[tid] += red[tid + st]; __syncthreads(); }
      float mean = red[0] * (1.f / 256.f); __syncthreads();
      float d = x - mean;
      red[tid] = d * d; __syncthreads();
      for (int st = 128; st > 0; st >>= 1) { if (tid < st) red[tid] += red[tid + st]; __syncthreads(); }
      float var = red[0] * (1.f / 256.f); __syncthreads();
      float xn = gam2[col] * d * rsqrtf(var + 1e-5f) + bet2[col];
      X2b[(size_t)tid * 512 + col] = f2bf(fmaxf(xn, 0.f));
    }
  }
  gbar(barall, 256);

  // D5: out[b,t] = sigmoid(X2[b]·Wm[t] + bm[t]) ; WG b
  {
    const int b = bid;
    float xa = bf2f(X2b[(size_t)b * 512 + tid]);
    float xb2 = bf2f(X2b[(size_t)b * 512 + 256 + tid]);
    float* red = (float*)lds;
    for (int t = 0; t < 12; ++t) {
      float p = xa * Wm[t * 512 + tid] + xb2 * Wm[t * 512 + 256 + tid];
      red[tid] = p; __syncthreads();
      for (int st = 128; st > 0; st >>= 1) { if (tid < st) red[tid] += red[tid + st]; __syncthreads(); }
      if (tid == 0) out[b * 12 + t] = sigf(red[0] + bm[t]);
      __syncthreads();
    }
  }
}

// ---------------- host launcher ----------------
extern "C" void kernel_launch(void* const* d_in, const int* in_sizes, int n_in,
                              void* d_out, int out_size, void* d_ws, size_t ws_size,
                              hipStream_t stream) {
  const int* smiles = (const int*)d_in[0];
  const float* emb = (const float*)d_in[1];
  const float* Wih0 = (const float*)d_in[2];
  const float* Whh0 = (const float*)d_in[3];
  const float* bih0 = (const float*)d_in[4];
  const float* bhh0 = (const float*)d_in[5];
  const float* Wih1 = (const float*)d_in[6];
  const float* Whh1 = (const float*)d_in[7];
  const float* bih1 = (const float*)d_in[8];
  const float* bhh1 = (const float*)d_in[9];
  const float* Wd1 = (const float*)d_in[10];
  const float* bd1 = (const float*)d_in[11];
  const float* g1 = (const float*)d_in[12];
  const float* be1 = (const float*)d_in[13];
  const float* Wd2 = (const float*)d_in[14];
  const float* bd2 = (const float*)d_in[15];
  const float* g2 = (const float*)d_in[16];
  const float* be2 = (const float*)d_in[17];
  const float* We = (const float*)d_in[18];
  const float* be = (const float*)d_in[19];
  char* ws = (char*)d_ws;
  float* out = (float*)d_out;

  // zero h double-buffers (1 MB) and barrier slots (4 KB) every call (deterministic)
  k_zero<<<256, 256, 0, stream>>>((uint4*)(ws + WS_H0B), 65536);
  k_zero<<<1, 256, 0, stream>>>((uint4*)(ws + WS_BAR), 256);
  // bf16 weight copies
  k_cvt<<<768, 256, 0, stream>>>(Whh0, (unsigned short*)(ws + WS_WHH0B), 786432);
  k_cvt<<<768, 256, 0, stream>>>(Wih1, (unsigned short*)(ws + WS_WIH1B), 786432);
  k_cvt<<<768, 256, 0, stream>>>(Whh1, (unsigned short*)(ws + WS_WHH1B), 786432);
  k_cvt<<<512, 256, 0, stream>>>(Wd1, (unsigned short*)(ws + WS_WD1B), 524288);
  k_cvt<<<512, 256, 0, stream>>>(Wd2, (unsigned short*)(ws + WS_WD2B), 524288);
  // fused emb@W_ih0^T lookup table and ensemble-mean head weights
  k_table<<<128, 256, 0, stream>>>(emb, Wih0, bih0, (float*)(ws + WS_TABLE0));
  k_wm<<<24, 256, 0, stream>>>(We, be, (float*)(ws + WS_WM), (float*)(ws + WS_BM));

  const int LDS_BYTES = 156160;  // 144K weights + 8.5K reduction scratch
  hipFuncSetAttribute((const void*)k_main, hipFuncAttributeMaxDynamicSharedMemorySize, LDS_BYTES);
  k_main<<<256, 256, LDS_BYTES, stream>>>(smiles, bhh0, bih1, bhh1, bd1, g1, be1,
                                          bd2, g2, be2, ws, out);
}

// Round 2
// 3857.609 us; speedup vs baseline: 1.5604x; 1.5604x over previous
//
#include <hip/hip_runtime.h>
#include <stdint.h>

// ---------------- workspace layout (bytes) ----------------
#define WS_TABLE0   0           // 128*1536*4 = 786432
#define WS_WHH0B    786432      // 1536*512*2
#define WS_WIH1B    2359296
#define WS_WHH1B    3932160
#define WS_WD1B     5505024     // 1024*512*2
#define WS_WD2B     6553600     // 512*1024*2
#define WS_WM       7602176     // 12*512*4
#define WS_BM       7626752     // 12*4 (padded)
#define WS_H0B      7627008     // 2*256*512*2
#define WS_H1B      8151296     // 2*256*512*2
#define WS_Y1       8675584     // 256*1024*4
#define WS_X1B      9724160     // 256*1024*2
#define WS_Y2       10248448    // 256*512*4
#define WS_X2B      10772736    // 256*512*2
#define WS_BAR      11034880    // flags[8][32] ints (1KB), barall at +2048

typedef __attribute__((ext_vector_type(8))) short bf16x8;
typedef __attribute__((ext_vector_type(4))) float f32x4;

__device__ __forceinline__ unsigned short f2bf(float f) {
  uint32_t u = __builtin_bit_cast(uint32_t, f);
  u += 0x7fffu + ((u >> 16) & 1u);
  return (unsigned short)(u >> 16);
}
__device__ __forceinline__ float bf2f(unsigned short s) {
  uint32_t u = ((uint32_t)s) << 16;
  return __builtin_bit_cast(float, u);
}
__device__ __forceinline__ float sigf(float x) { return 1.f / (1.f + __expf(-x)); }
__device__ __forceinline__ float tanhs(float x) {
  x = fminf(fmaxf(x, -10.f), 10.f);
  float e = __expf(2.f * x);
  return (e - 1.f) / (e + 1.f);
}

// write-through store (sc0 sc1 -> visible at L3, no dirty L2 line)
__device__ __forceinline__ void st_wt(unsigned short* p, unsigned short v) {
  __hip_atomic_store(p, v, __ATOMIC_RELAXED, __HIP_MEMORY_SCOPE_AGENT);
}

// heavyweight device barrier (dense head only; includes full release fence)
__device__ __forceinline__ void gbar(int* bar, int expected) {
  __syncthreads();
  if (threadIdx.x == 0) {
    __threadfence();
    int g0 = __hip_atomic_load(bar + 1, __ATOMIC_RELAXED, __HIP_MEMORY_SCOPE_AGENT);
    int a = __hip_atomic_fetch_add(bar, 1, __ATOMIC_ACQ_REL, __HIP_MEMORY_SCOPE_AGENT);
    if (a == expected - 1) {
      __hip_atomic_store(bar, 0, __ATOMIC_RELAXED, __HIP_MEMORY_SCOPE_AGENT);
      __hip_atomic_fetch_add(bar + 1, 1, __ATOMIC_RELEASE, __HIP_MEMORY_SCOPE_AGENT);
    } else {
      while (__hip_atomic_load(bar + 1, __ATOMIC_RELAXED, __HIP_MEMORY_SCOPE_AGENT) == g0) {
        __builtin_amdgcn_s_sleep(1);
      }
    }
    __threadfence();
  }
  __syncthreads();
}

// ---------------- prep kernels ----------------
__global__ void k_zero(uint4* p, int n16) {
  int i = blockIdx.x * 256 + threadIdx.x;
  if (i < n16) p[i] = make_uint4(0u, 0u, 0u, 0u);
}

__global__ void k_cvt(const float* __restrict__ src, unsigned short* __restrict__ dst, int n) {
  int i = (blockIdx.x * 256 + threadIdx.x) * 4;
  if (i < n) {
    float4 v = *(const float4*)(src + i);
    dst[i + 0] = f2bf(v.x);
    dst[i + 1] = f2bf(v.y);
    dst[i + 2] = f2bf(v.z);
    dst[i + 3] = f2bf(v.w);
  }
}

__global__ void k_table(const float* __restrict__ emb, const float* __restrict__ Wih0,
                        const float* __restrict__ bih0, float* __restrict__ table) {
  __shared__ float e[512];
  int v = blockIdx.x;
  for (int i = threadIdx.x; i < 512; i += 256) e[i] = emb[v * 512 + i];
  __syncthreads();
  for (int cidx = threadIdx.x; cidx < 1536; cidx += 256) {
    const float* w = Wih0 + (size_t)cidx * 512;
    float s = 0.f;
    #pragma unroll 4
    for (int k = 0; k < 512; k += 4) {
      float4 w4 = *(const float4*)(w + k);
      s += w4.x * e[k] + w4.y * e[k + 1] + w4.z * e[k + 2] + w4.w * e[k + 3];
    }
    table[(size_t)v * 1536 + cidx] = s + bih0[cidx];
  }
}

__global__ void k_wm(const float* __restrict__ We, const float* __restrict__ be,
                     float* __restrict__ Wm, float* __restrict__ bm) {
  int i = blockIdx.x * 256 + threadIdx.x;
  if (i < 12 * 512) {
    int t = i / 512, d = i % 512;
    float s = 0.f;
    for (int e = 0; e < 5; ++e) s += We[((size_t)e * 12 + t) * 512 + d];
    Wm[i] = s * 0.2f;
  }
  if (i < 12) {
    float s = 0.f;
    for (int e = 0; e < 5; ++e) s += be[e * 12 + i];
    bm[i] = s * 0.2f;
  }
}

// ---------------- persistent main kernel ----------------
__global__ void __launch_bounds__(256, 1) k_main(
    const int* __restrict__ smiles,
    const float* __restrict__ bhh0,
    const float* __restrict__ bih1,
    const float* __restrict__ bhh1,
    const float* __restrict__ bd1,
    const float* __restrict__ gam1,
    const float* __restrict__ bet1,
    const float* __restrict__ bd2,
    const float* __restrict__ gam2,
    const float* __restrict__ bet2,
    char* __restrict__ ws,
    float* __restrict__ out) {
  extern __shared__ char lds[];
  const int tid = threadIdx.x, bid = blockIdx.x;
  const int lane = tid & 63, wave = tid >> 6;
  const int grp = bid & 7, member = bid >> 3;
  const int hc = member * 16;
  const int l15 = lane & 15, l4 = lane >> 4;

  const float* table0 = (const float*)(ws + WS_TABLE0);
  const unsigned short* Whh0b = (const unsigned short*)(ws + WS_WHH0B);
  const unsigned short* Wih1b = (const unsigned short*)(ws + WS_WIH1B);
  const unsigned short* Whh1b = (const unsigned short*)(ws + WS_WHH1B);
  const unsigned short* Wd1b = (const unsigned short*)(ws + WS_WD1B);
  const unsigned short* Wd2b = (const unsigned short*)(ws + WS_WD2B);
  const float* Wm = (const float*)(ws + WS_WM);
  const float* bm = (const float*)(ws + WS_BM);
  unsigned short* h0b = (unsigned short*)(ws + WS_H0B);
  unsigned short* h1b = (unsigned short*)(ws + WS_H1B);
  float* Y1 = (float*)(ws + WS_Y1);
  unsigned short* X1b = (unsigned short*)(ws + WS_X1B);
  float* Y2 = (float*)(ws + WS_Y2);
  unsigned short* X2b = (unsigned short*)(ws + WS_X2B);
  int* flags = (int*)(ws + WS_BAR) + grp * 32;
  int* barall = (int*)(ws + WS_BAR + 2048);

  float* accS = (float*)(lds + 147456);

  // ---- stage weight slices into LDS (XOR-swizzled at 16B granularity) ----
  for (int u = tid; u < 3 * 48 * 64; u += 256) {
    int mat = u / (48 * 64);
    int rem = u - mat * (48 * 64);
    int r = rem >> 6, c16 = rem & 63;
    const unsigned short* src = (mat == 0) ? Whh0b : (mat == 1) ? Wih1b : Whh1b;
    int grow = (r >> 4) * 512 + hc + (r & 15);
    uint4 v = *(const uint4*)(src + (size_t)grow * 512 + c16 * 8);
    int off = mat * 49152 + r * 1024 + ((c16 * 16) ^ ((r & 7) << 4));
    *(uint4*)(lds + off) = v;
  }
  __syncthreads();

  const int c = hc + l15;
  const float bh0r = bhh0[c], bh0z = bhh0[512 + c], bh0n = bhh0[1024 + c];
  const float b1r = bih1[c] + bhh1[c];
  const float b1z = bih1[512 + c] + bhh1[512 + c];
  const float b1xn = bih1[1024 + c];
  const float b1hn = bhh1[1024 + c];
  const int swz = (l15 & 7) << 4;

  auto ldsB = [&](int mat, int gate, int kc) -> bf16x8 {
    int off = mat * 49152 + (gate * 16 + l15) * 1024 + ((((kc << 6) + (l4 << 4))) ^ swz);
    return *(const bf16x8*)(lds + off);
  };
  auto loadA = [&](const unsigned short* base, int kc) -> bf16x8 {
    return *(const bf16x8*)(base + (size_t)l15 * 512 + (kc << 5) + (l4 << 3));
  };

  float h0m[8], h1m[4];
  #pragma unroll
  for (int i = 0; i < 8; ++i) h0m[i] = 0.f;
  #pragma unroll
  for (int i = 0; i < 4; ++i) h1m[i] = 0.f;

  const int rowbase = grp * 32;
  const f32x4 z4 = {0.f, 0.f, 0.f, 0.f};

  // token prefetch (wave0 only, its 8 rows): tokens for step 0
  int tokp[8];
  if (wave == 0) {
    #pragma unroll
    for (int mt = 0; mt < 2; ++mt)
      #pragma unroll
      for (int q = 0; q < 4; ++q)
        tokp[mt * 4 + q] = smiles[(size_t)(rowbase + mt * 16 + 4 * l4 + q) * 256 + 0];
  }

  for (int s = 0; s <= 256; ++s) {
    const unsigned short* h0rd = h0b + (size_t)((s + 1) & 1) * 131072 + (size_t)rowbase * 512;
    const unsigned short* h1rd = h1b + (size_t)(s & 1) * 131072 + (size_t)rowbase * 512;

    f32x4 pr[2], pz[2], pxn[2], phn[2];
    pr[0] = z4; pr[1] = z4; pz[0] = z4; pz[1] = z4;
    pxn[0] = z4; pxn[1] = z4; phn[0] = z4; phn[1] = z4;

    if (wave == 0) {
      if (s < 256) {
        // gathers for step s (tokens prefetched); prefetch tokens for s+1
        float xg[2][4][3];
        int tokn[8];
        #pragma unroll
        for (int mt = 0; mt < 2; ++mt) {
          #pragma unroll
          for (int q = 0; q < 4; ++q) {
            int b = rowbase + mt * 16 + 4 * l4 + q;
            int tok = tokp[mt * 4 + q];
            const float* tb = table0 + (size_t)tok * 1536 + c;
            xg[mt][q][0] = tb[0];
            xg[mt][q][1] = tb[512];
            xg[mt][q][2] = tb[1024];
            if (s + 1 < 256) tokn[mt * 4 + q] = smiles[(size_t)b * 256 + s + 1];
          }
        }
        f32x4 acc[3][2];
        #pragma unroll
        for (int gi = 0; gi < 3; ++gi) { acc[gi][0] = z4; acc[gi][1] = z4; }
        #pragma unroll 4
        for (int kc = 0; kc < 16; ++kc) {
          bf16x8 a0 = loadA(h0rd, kc);
          bf16x8 a1 = loadA(h0rd + 16 * 512, kc);
          #pragma unroll
          for (int gi = 0; gi < 3; ++gi) {
            bf16x8 bb = ldsB(0, gi, kc);
            acc[gi][0] = __builtin_amdgcn_mfma_f32_16x16x32_bf16(a0, bb, acc[gi][0], 0, 0, 0);
            acc[gi][1] = __builtin_amdgcn_mfma_f32_16x16x32_bf16(a1, bb, acc[gi][1], 0, 0, 0);
          }
        }
        unsigned short* h0wr = h0b + (size_t)(s & 1) * 131072;
        #pragma unroll
        for (int mt = 0; mt < 2; ++mt) {
          #pragma unroll
          for (int q = 0; q < 4; ++q) {
            int b = rowbase + mt * 16 + 4 * l4 + q;
            float rr = sigf(xg[mt][q][0] + acc[0][mt][q] + bh0r);
            float zz = sigf(xg[mt][q][1] + acc[1][mt][q] + bh0z);
            float nn = tanhs(xg[mt][q][2] + rr * (acc[2][mt][q] + bh0n));
            float hv = (1.f - zz) * nn + zz * h0m[mt * 4 + q];
            h0m[mt * 4 + q] = hv;
            st_wt(h0wr + (size_t)b * 512 + c, f2bf(hv));
          }
        }
        #pragma unroll
        for (int i = 0; i < 8; ++i) tokp[i] = tokn[i];
      }
    } else {
      if (s >= 1) {
        const int wi = wave - 1;
        const int kc0 = (wi == 0) ? 0 : (wi == 1) ? 6 : 11;
        const int kc1 = (wi == 0) ? 6 : (wi == 1) ? 11 : 16;
        #pragma unroll 2
        for (int kc = kc0; kc < kc1; ++kc) {
          bf16x8 x0 = loadA(h0rd, kc);
          bf16x8 x1 = loadA(h0rd + 16 * 512, kc);
          bf16x8 y0 = loadA(h1rd, kc);
          bf16x8 y1 = loadA(h1rd + 16 * 512, kc);
          bf16x8 bxr = ldsB(1, 0, kc), bxz = ldsB(1, 1, kc), bxn = ldsB(1, 2, kc);
          bf16x8 bhr = ldsB(2, 0, kc), bhz = ldsB(2, 1, kc), bhn = ldsB(2, 2, kc);
          pr[0] = __builtin_amdgcn_mfma_f32_16x16x32_bf16(x0, bxr, pr[0], 0, 0, 0);
          pr[0] = __builtin_amdgcn_mfma_f32_16x16x32_bf16(y0, bhr, pr[0], 0, 0, 0);
          pr[1] = __builtin_amdgcn_mfma_f32_16x16x32_bf16(x1, bxr, pr[1], 0, 0, 0);
          pr[1] = __builtin_amdgcn_mfma_f32_16x16x32_bf16(y1, bhr, pr[1], 0, 0, 0);
          pz[0] = __builtin_amdgcn_mfma_f32_16x16x32_bf16(x0, bxz, pz[0], 0, 0, 0);
          pz[0] = __builtin_amdgcn_mfma_f32_16x16x32_bf16(y0, bhz, pz[0], 0, 0, 0);
          pz[1] = __builtin_amdgcn_mfma_f32_16x16x32_bf16(x1, bxz, pz[1], 0, 0, 0);
          pz[1] = __builtin_amdgcn_mfma_f32_16x16x32_bf16(y1, bhz, pz[1], 0, 0, 0);
          pxn[0] = __builtin_amdgcn_mfma_f32_16x16x32_bf16(x0, bxn, pxn[0], 0, 0, 0);
          pxn[1] = __builtin_amdgcn_mfma_f32_16x16x32_bf16(x1, bxn, pxn[1], 0, 0, 0);
          phn[0] = __builtin_amdgcn_mfma_f32_16x16x32_bf16(y0, bhn, phn[0], 0, 0, 0);
          phn[1] = __builtin_amdgcn_mfma_f32_16x16x32_bf16(y1, bhn, phn[1], 0, 0, 0);
        }
      }
    }

    // cross-wave K-reduction of L1 partials
    #pragma unroll
    for (int r = 0; r < 3; ++r) {
      __syncthreads();
      if (wave >= 1 && s >= 1) {
        const int wi = wave - 1;
        #pragma unroll
        for (int j = 0; j < 8; ++j) {
          if (j % 3 == (wi + r) % 3) {
            const int gk = j >> 1, mt = j & 1;
            f32x4 v = (gk == 0) ? pr[mt] : (gk == 1) ? pz[mt] : (gk == 2) ? pxn[mt] : phn[mt];
            float* dstp = accS + j * 272;
            #pragma unroll
            for (int q = 0; q < 4; ++q) {
              int idx = (4 * l4 + q) * 17 + l15;
              if (r == 0) dstp[idx] = v[q];
              else dstp[idx] += v[q];
            }
          }
        }
      }
    }
    __syncthreads();
    if ((wave == 1 || wave == 2) && s >= 1) {
      const int mt = wave - 1;
      unsigned short* h1wr = h1b + (size_t)((s + 1) & 1) * 131072;
      #pragma unroll
      for (int q = 0; q < 4; ++q) {
        int idx = (4 * l4 + q) * 17 + l15;
        float rr = sigf(accS[(0 * 2 + mt) * 272 + idx] + b1r);
        float zz = sigf(accS[(1 * 2 + mt) * 272 + idx] + b1z);
        float nn = tanhs(accS[(2 * 2 + mt) * 272 + idx] + b1xn +
                         rr * (accS[(3 * 2 + mt) * 272 + idx] + b1hn));
        float hv = (1.f - zz) * nn + zz * h1m[q];
        h1m[q] = hv;
        int b = rowbase + mt * 16 + 4 * l4 + q;
        st_wt(h1wr + (size_t)b * 512 + c, f2bf(hv));
      }
    }

    // ---- fence-free step barrier: vmcnt drain -> flag -> poll -> inv ----
    asm volatile("s_waitcnt vmcnt(0)" ::: "memory");
    __syncthreads();
    if (tid == 0)
      __hip_atomic_store(&flags[member], s + 1, __ATOMIC_RELAXED, __HIP_MEMORY_SCOPE_AGENT);
    if (tid < 32) {
      while (__hip_atomic_load(&flags[tid], __ATOMIC_RELAXED, __HIP_MEMORY_SCOPE_AGENT) < s + 1) {
      }
    }
    __builtin_amdgcn_fence(__ATOMIC_ACQUIRE, "agent");
    __syncthreads();
  }

  // ================= dense head =================
  gbar(barall, 256);

  {
    const int mi = bid & 15, ni = bid >> 4;
    const unsigned short* A = h1b + 131072 + (size_t)(16 * mi) * 512;
    const int colb = 64 * ni + 16 * wave;
    f32x4 acc = z4;
    #pragma unroll 4
    for (int kc = 0; kc < 16; ++kc) {
      bf16x8 a = loadA(A, kc);
      bf16x8 bb = *(const bf16x8*)(Wd1b + (size_t)(colb + l15) * 512 + (kc << 5) + (l4 << 3));
      acc = __builtin_amdgcn_mfma_f32_16x16x32_bf16(a, bb, acc, 0, 0, 0);
    }
    #pragma unroll
    for (int q = 0; q < 4; ++q) {
      int row = 16 * mi + 4 * l4 + q, col = colb + l15;
      Y1[(size_t)row * 1024 + col] = acc[q] + bd1[col];
    }
  }
  gbar(barall, 256);

  {
    float* red = (float*)lds;
    for (int cc = 0; cc < 4; ++cc) {
      int col = bid * 4 + cc;
      float x = Y1[(size_t)tid * 1024 + col];
      red[tid] = x; __syncthreads();
      for (int st = 128; st > 0; st >>= 1) { if (tid < st) red[tid] += red[tid + st]; __syncthreads(); }
      float mean = red[0] * (1.f / 256.f); __syncthreads();
      float d = x - mean;
      red[tid] = d * d; __syncthreads();
      for (int st = 128; st > 0; st >>= 1) { if (tid < st) red[tid] += red[tid + st]; __syncthreads(); }
      float var = red[0] * (1.f / 256.f); __syncthreads();
      float xn = gam1[col] * d * rsqrtf(var + 1e-5f) + bet1[col];
      X1b[(size_t)tid * 1024 + col] = f2bf(fmaxf(xn, 0.f));
    }
  }
  gbar(barall, 256);

  {
    const int mi = bid & 15, ni = bid >> 4;
    if (wave < 2) {
      const unsigned short* A = X1b + (size_t)(16 * mi) * 1024;
      const int colb = 32 * ni + 16 * wave;
      f32x4 acc = z4;
      #pragma unroll 4
      for (int kc = 0; kc < 32; ++kc) {
        bf16x8 a = *(const bf16x8*)(A + (size_t)l15 * 1024 + (kc << 5) + (l4 << 3));
        bf16x8 bb = *(const bf16x8*)(Wd2b + (size_t)(colb + l15) * 1024 + (kc << 5) + (l4 << 3));
        acc = __builtin_amdgcn_mfma_f32_16x16x32_bf16(a, bb, acc, 0, 0, 0);
      }
      #pragma unroll
      for (int q = 0; q < 4; ++q) {
        int row = 16 * mi + 4 * l4 + q, col = colb + l15;
        Y2[(size_t)row * 512 + col] = acc[q] + bd2[col];
      }
    }
  }
  gbar(barall, 256);

  {
    float* red = (float*)lds;
    for (int cc = 0; cc < 2; ++cc) {
      int col = bid * 2 + cc;
      float x = Y2[(size_t)tid * 512 + col];
      red[tid] = x; __syncthreads();
      for (int st = 128; st > 0; st >>= 1) { if (tid < st) red[tid] += red[tid + st]; __syncthreads(); }
      float mean = red[0] * (1.f / 256.f); __syncthreads();
      float d = x - mean;
      red[tid] = d * d; __syncthreads();
      for (int st = 128; st > 0; st >>= 1) { if (tid < st) red[tid] += red[tid + st]; __syncthreads(); }
      float var = red[0] * (1.f / 256.f); __syncthreads();
      float xn = gam2[col] * d * rsqrtf(var + 1e-5f) + bet2[col];
      X2b[(size_t)tid * 512 + col] = f2bf(fmaxf(xn, 0.f));
    }
  }
  gbar(barall, 256);

  {
    const int b = bid;
    float xa = bf2f(X2b[(size_t)b * 512 + tid]);
    float xb2 = bf2f(X2b[(size_t)b * 512 + 256 + tid]);
    float* red = (float*)lds;
    for (int t = 0; t < 12; ++t) {
      float p = xa * Wm[t * 512 + tid] + xb2 * Wm[t * 512 + 256 + tid];
      red[tid] = p; __syncthreads();
      for (int st = 128; st > 0; st >>= 1) { if (tid < st) red[tid] += red[tid + st]; __syncthreads(); }
      if (tid == 0) out[b * 12 + t] = sigf(red[0] + bm[t]);
      __syncthreads();
    }
  }
}

// ---------------- host launcher ----------------
extern "C" void kernel_launch(void* const* d_in, const int* in_sizes, int n_in,
                              void* d_out, int out_size, void* d_ws, size_t ws_size,
                              hipStream_t stream) {
  const int* smiles = (const int*)d_in[0];
  const float* emb = (const float*)d_in[1];
  const float* Wih0 = (const float*)d_in[2];
  const float* Whh0 = (const float*)d_in[3];
  const float* bih0 = (const float*)d_in[4];
  const float* bhh0 = (const float*)d_in[5];
  const float* Wih1 = (const float*)d_in[6];
  const float* Whh1 = (const float*)d_in[7];
  const float* bih1 = (const float*)d_in[8];
  const float* bhh1 = (const float*)d_in[9];
  const float* Wd1 = (const float*)d_in[10];
  const float* bd1 = (const float*)d_in[11];
  const float* g1 = (const float*)d_in[12];
  const float* be1 = (const float*)d_in[13];
  const float* Wd2 = (const float*)d_in[14];
  const float* bd2 = (const float*)d_in[15];
  const float* g2 = (const float*)d_in[16];
  const float* be2 = (const float*)d_in[17];
  const float* We = (const float*)d_in[18];
  const float* be = (const float*)d_in[19];
  char* ws = (char*)d_ws;
  float* out = (float*)d_out;

  k_zero<<<256, 256, 0, stream>>>((uint4*)(ws + WS_H0B), 65536);
  k_zero<<<1, 256, 0, stream>>>((uint4*)(ws + WS_BAR), 256);
  k_cvt<<<768, 256, 0, stream>>>(Whh0, (unsigned short*)(ws + WS_WHH0B), 786432);
  k_cvt<<<768, 256, 0, stream>>>(Wih1, (unsigned short*)(ws + WS_WIH1B), 786432);
  k_cvt<<<768, 256, 0, stream>>>(Whh1, (unsigned short*)(ws + WS_WHH1B), 786432);
  k_cvt<<<512, 256, 0, stream>>>(Wd1, (unsigned short*)(ws + WS_WD1B), 524288);
  k_cvt<<<512, 256, 0, stream>>>(Wd2, (unsigned short*)(ws + WS_WD2B), 524288);
  k_table<<<128, 256, 0, stream>>>(emb, Wih0, bih0, (float*)(ws + WS_TABLE0));
  k_wm<<<24, 256, 0, stream>>>(We, be, (float*)(ws + WS_WM), (float*)(ws + WS_BM));

  const int LDS_BYTES = 156160;
  hipFuncSetAttribute((const void*)k_main, hipFuncAttributeMaxDynamicSharedMemorySize, LDS_BYTES);
  k_main<<<256, 256, LDS_BYTES, stream>>>(smiles, bhh0, bih1, bhh1, bd1, g1, be1,
                                          bd2, g2, be2, ws, out);
}

// Round 3
// 2763.476 us; speedup vs baseline: 2.1782x; 1.3959x over previous
//
#include <hip/hip_runtime.h>
#include <stdint.h>

// ---------------- workspace layout (bytes) ----------------
#define WS_TABLE0   0           // 128*1536*4 = 786432
#define WS_WHH0B    786432      // 1536*512*2
#define WS_WIH1B    2359296
#define WS_WHH1B    3932160
#define WS_WD1B     5505024     // 1024*512*2
#define WS_WD2B     6553600     // 512*1024*2
#define WS_WM       7602176     // 12*512*4
#define WS_BM       7626752     // 12*4 (padded)
#define WS_H0B      7627008     // 2*256*512*2
#define WS_H1B      8151296     // 2*256*512*2
#define WS_Y1       8675584     // 256*1024*4
#define WS_X1B      9724160     // 256*1024*2
#define WS_Y2       10248448    // 256*512*4
#define WS_X2B      10772736    // 256*512*2
#define WS_BAR      11034880    // flags[8][32] ints (1KB), barall at +2048

typedef __attribute__((ext_vector_type(8))) short bf16x8;
typedef __attribute__((ext_vector_type(4))) float f32x4;

__device__ __forceinline__ unsigned short f2bf(float f) {
  uint32_t u = __builtin_bit_cast(uint32_t, f);
  u += 0x7fffu + ((u >> 16) & 1u);
  return (unsigned short)(u >> 16);
}
__device__ __forceinline__ float bf2f(unsigned short s) {
  uint32_t u = ((uint32_t)s) << 16;
  return __builtin_bit_cast(float, u);
}
__device__ __forceinline__ float sigf(float x) { return 1.f / (1.f + __expf(-x)); }
__device__ __forceinline__ float tanhs(float x) {
  x = fminf(fmaxf(x, -10.f), 10.f);
  float e = __expf(2.f * x);
  return (e - 1.f) / (e + 1.f);
}

// write-through store (sc0 sc1 -> visible at L3, no dirty L2 line)
__device__ __forceinline__ void st_wt(unsigned short* p, unsigned short v) {
  __hip_atomic_store(p, v, __ATOMIC_RELAXED, __HIP_MEMORY_SCOPE_AGENT);
}

// heavyweight device barrier (dense head only)
__device__ __forceinline__ void gbar(int* bar, int expected) {
  __syncthreads();
  if (threadIdx.x == 0) {
    __threadfence();
    int g0 = __hip_atomic_load(bar + 1, __ATOMIC_RELAXED, __HIP_MEMORY_SCOPE_AGENT);
    int a = __hip_atomic_fetch_add(bar, 1, __ATOMIC_ACQ_REL, __HIP_MEMORY_SCOPE_AGENT);
    if (a == expected - 1) {
      __hip_atomic_store(bar, 0, __ATOMIC_RELAXED, __HIP_MEMORY_SCOPE_AGENT);
      __hip_atomic_fetch_add(bar + 1, 1, __ATOMIC_RELEASE, __HIP_MEMORY_SCOPE_AGENT);
    } else {
      while (__hip_atomic_load(bar + 1, __ATOMIC_RELAXED, __HIP_MEMORY_SCOPE_AGENT) == g0) {
        __builtin_amdgcn_s_sleep(1);
      }
    }
    __threadfence();
  }
  __syncthreads();
}

// ---------------- prep kernels ----------------
__global__ void k_zero(uint4* p, int n16) {
  int i = blockIdx.x * 256 + threadIdx.x;
  if (i < n16) p[i] = make_uint4(0u, 0u, 0u, 0u);
}

__global__ void k_cvt(const float* __restrict__ src, unsigned short* __restrict__ dst, int n) {
  int i = (blockIdx.x * 256 + threadIdx.x) * 4;
  if (i < n) {
    float4 v = *(const float4*)(src + i);
    dst[i + 0] = f2bf(v.x);
    dst[i + 1] = f2bf(v.y);
    dst[i + 2] = f2bf(v.z);
    dst[i + 3] = f2bf(v.w);
  }
}

__global__ void k_table(const float* __restrict__ emb, const float* __restrict__ Wih0,
                        const float* __restrict__ bih0, float* __restrict__ table) {
  __shared__ float e[512];
  int v = blockIdx.x;
  for (int i = threadIdx.x; i < 512; i += 256) e[i] = emb[v * 512 + i];
  __syncthreads();
  for (int cidx = threadIdx.x; cidx < 1536; cidx += 256) {
    const float* w = Wih0 + (size_t)cidx * 512;
    float s = 0.f;
    #pragma unroll 4
    for (int k = 0; k < 512; k += 4) {
      float4 w4 = *(const float4*)(w + k);
      s += w4.x * e[k] + w4.y * e[k + 1] + w4.z * e[k + 2] + w4.w * e[k + 3];
    }
    table[(size_t)v * 1536 + cidx] = s + bih0[cidx];
  }
}

__global__ void k_wm(const float* __restrict__ We, const float* __restrict__ be,
                     float* __restrict__ Wm, float* __restrict__ bm) {
  int i = blockIdx.x * 256 + threadIdx.x;
  if (i < 12 * 512) {
    int t = i / 512, d = i % 512;
    float s = 0.f;
    for (int e = 0; e < 5; ++e) s += We[((size_t)e * 12 + t) * 512 + d];
    Wm[i] = s * 0.2f;
  }
  if (i < 12) {
    float s = 0.f;
    for (int e = 0; e < 5; ++e) s += be[e * 12 + i];
    bm[i] = s * 0.2f;
  }
}

// ---------------- persistent main kernel ----------------
__global__ void __launch_bounds__(256, 1) k_main(
    const int* __restrict__ smiles,
    const float* __restrict__ bhh0,
    const float* __restrict__ bih1,
    const float* __restrict__ bhh1,
    const float* __restrict__ bd1,
    const float* __restrict__ gam1,
    const float* __restrict__ bet1,
    const float* __restrict__ bd2,
    const float* __restrict__ gam2,
    const float* __restrict__ bet2,
    char* __restrict__ ws,
    float* __restrict__ out) {
  extern __shared__ char lds[];
  const int tid = threadIdx.x, bid = blockIdx.x;
  const int lane = tid & 63, wave = tid >> 6;
  const int grp = bid & 7, member = bid >> 3;
  const int hc = member * 16;
  const int l15 = lane & 15, l4 = lane >> 4;

  const float* table0 = (const float*)(ws + WS_TABLE0);
  const unsigned short* Whh0b = (const unsigned short*)(ws + WS_WHH0B);
  const unsigned short* Wih1b = (const unsigned short*)(ws + WS_WIH1B);
  const unsigned short* Whh1b = (const unsigned short*)(ws + WS_WHH1B);
  const unsigned short* Wd1b = (const unsigned short*)(ws + WS_WD1B);
  const unsigned short* Wd2b = (const unsigned short*)(ws + WS_WD2B);
  const float* Wm = (const float*)(ws + WS_WM);
  const float* bm = (const float*)(ws + WS_BM);
  unsigned short* h0b = (unsigned short*)(ws + WS_H0B);
  unsigned short* h1b = (unsigned short*)(ws + WS_H1B);
  float* Y1 = (float*)(ws + WS_Y1);
  unsigned short* X1b = (unsigned short*)(ws + WS_X1B);
  float* Y2 = (float*)(ws + WS_Y2);
  unsigned short* X2b = (unsigned short*)(ws + WS_X2B);
  int* flags = (int*)(ws + WS_BAR) + grp * 32;
  int* barall = (int*)(ws + WS_BAR + 2048);

  float* accS = (float*)(lds + 147456);

  // ---- stage weight slices into LDS (XOR-swizzled at 16B granularity) ----
  for (int u = tid; u < 3 * 48 * 64; u += 256) {
    int mat = u / (48 * 64);
    int rem = u - mat * (48 * 64);
    int r = rem >> 6, c16 = rem & 63;
    const unsigned short* src = (mat == 0) ? Whh0b : (mat == 1) ? Wih1b : Whh1b;
    int grow = (r >> 4) * 512 + hc + (r & 15);
    uint4 v = *(const uint4*)(src + (size_t)grow * 512 + c16 * 8);
    int off = mat * 49152 + r * 1024 + ((c16 * 16) ^ ((r & 7) << 4));
    *(uint4*)(lds + off) = v;
  }
  __syncthreads();

  const int c = hc + l15;
  const float bh0r = bhh0[c], bh0z = bhh0[512 + c], bh0n = bhh0[1024 + c];
  const float b1r = bih1[c] + bhh1[c];
  const float b1z = bih1[512 + c] + bhh1[512 + c];
  const float b1xn = bih1[1024 + c];
  const float b1hn = bhh1[1024 + c];
  const int swz = (l15 & 7) << 4;

  auto ldsB = [&](int mat, int gate, int kc) -> bf16x8 {
    int off = mat * 49152 + (gate * 16 + l15) * 1024 + ((((kc << 6) + (l4 << 4))) ^ swz);
    return *(const bf16x8*)(lds + off);
  };
  auto loadA = [&](const unsigned short* base, int kc) -> bf16x8 {
    return *(const bf16x8*)(base + (size_t)l15 * 512 + (kc << 5) + (l4 << 3));
  };

  float h0m[8], h1m[4];
  #pragma unroll
  for (int i = 0; i < 8; ++i) h0m[i] = 0.f;
  #pragma unroll
  for (int i = 0; i < 4; ++i) h1m[i] = 0.f;

  const int rowbase = grp * 32;
  const f32x4 z4 = {0.f, 0.f, 0.f, 0.f};

  // token prefetch (wave0 only, its 8 rows): tokens for step 0
  int tokp[8];
  if (wave == 0) {
    #pragma unroll
    for (int mt = 0; mt < 2; ++mt)
      #pragma unroll
      for (int q = 0; q < 4; ++q)
        tokp[mt * 4 + q] = smiles[(size_t)(rowbase + mt * 16 + 4 * l4 + q) * 256 + 0];
  }

  for (int s = 0; s <= 256; ++s) {
    const unsigned short* h0rd = h0b + (size_t)((s + 1) & 1) * 131072 + (size_t)rowbase * 512;
    const unsigned short* h1rd = h1b + (size_t)(s & 1) * 131072 + (size_t)rowbase * 512;

    f32x4 pr[2], pz[2], pxn[2], phn[2];
    pr[0] = z4; pr[1] = z4; pz[0] = z4; pz[1] = z4;
    pxn[0] = z4; pxn[1] = z4; phn[0] = z4; phn[1] = z4;

    if (wave == 0) {
      if (s < 256) {
        // gathers for step s + next-token prefetch (independent of GEMM)
        float xg[2][4][3];
        int tokn[8];
        #pragma unroll
        for (int mt = 0; mt < 2; ++mt) {
          #pragma unroll
          for (int q = 0; q < 4; ++q) {
            int b = rowbase + mt * 16 + 4 * l4 + q;
            const float* tb = table0 + (size_t)tokp[mt * 4 + q] * 1536 + c;
            xg[mt][q][0] = tb[0];
            xg[mt][q][1] = tb[512];
            xg[mt][q][2] = tb[1024];
            tokn[mt * 4 + q] = (s + 1 < 256) ? smiles[(size_t)b * 256 + s + 1] : 0;
          }
        }
        // hoist ALL A-fragment loads (32 independent 16B loads -> 1 L3 round trip)
        bf16x8 A0[16], A1[16];
        #pragma unroll
        for (int kc = 0; kc < 16; ++kc) {
          A0[kc] = loadA(h0rd, kc);
          A1[kc] = loadA(h0rd + 16 * 512, kc);
        }
        f32x4 acc[3][2];
        #pragma unroll
        for (int gi = 0; gi < 3; ++gi) { acc[gi][0] = z4; acc[gi][1] = z4; }
        #pragma unroll
        for (int kc = 0; kc < 16; ++kc) {
          #pragma unroll
          for (int gi = 0; gi < 3; ++gi) {
            bf16x8 bb = ldsB(0, gi, kc);
            acc[gi][0] = __builtin_amdgcn_mfma_f32_16x16x32_bf16(A0[kc], bb, acc[gi][0], 0, 0, 0);
            acc[gi][1] = __builtin_amdgcn_mfma_f32_16x16x32_bf16(A1[kc], bb, acc[gi][1], 0, 0, 0);
          }
        }
        unsigned short* h0wr = h0b + (size_t)(s & 1) * 131072;
        #pragma unroll
        for (int mt = 0; mt < 2; ++mt) {
          #pragma unroll
          for (int q = 0; q < 4; ++q) {
            int b = rowbase + mt * 16 + 4 * l4 + q;
            float rr = sigf(xg[mt][q][0] + acc[0][mt][q] + bh0r);
            float zz = sigf(xg[mt][q][1] + acc[1][mt][q] + bh0z);
            float nn = tanhs(xg[mt][q][2] + rr * (acc[2][mt][q] + bh0n));
            float hv = (1.f - zz) * nn + zz * h0m[mt * 4 + q];
            h0m[mt * 4 + q] = hv;
            st_wt(h0wr + (size_t)b * 512 + c, f2bf(hv));
          }
        }
        #pragma unroll
        for (int i = 0; i < 8; ++i) tokp[i] = tokn[i];
      }
    } else {
      if (s >= 1) {
        const int wi = wave - 1;
        const int kc0 = (wi == 0) ? 0 : (wi == 1) ? 6 : 11;
        const int nk = (wi == 0) ? 6 : 5;
        // hoist all A loads for this wave's K-range
        bf16x8 X0[6], X1[6], Y0[6], Y1[6];
        #pragma unroll
        for (int i = 0; i < 6; ++i) {
          if (i < nk) {
            int kc = kc0 + i;
            X0[i] = loadA(h0rd, kc);
            X1[i] = loadA(h0rd + 16 * 512, kc);
            Y0[i] = loadA(h1rd, kc);
            Y1[i] = loadA(h1rd + 16 * 512, kc);
          }
        }
        #pragma unroll
        for (int i = 0; i < 6; ++i) {
          if (i < nk) {
            int kc = kc0 + i;
            bf16x8 bxr = ldsB(1, 0, kc), bxz = ldsB(1, 1, kc), bxn = ldsB(1, 2, kc);
            bf16x8 bhr = ldsB(2, 0, kc), bhz = ldsB(2, 1, kc), bhn = ldsB(2, 2, kc);
            pr[0] = __builtin_amdgcn_mfma_f32_16x16x32_bf16(X0[i], bxr, pr[0], 0, 0, 0);
            pr[0] = __builtin_amdgcn_mfma_f32_16x16x32_bf16(Y0[i], bhr, pr[0], 0, 0, 0);
            pr[1] = __builtin_amdgcn_mfma_f32_16x16x32_bf16(X1[i], bxr, pr[1], 0, 0, 0);
            pr[1] = __builtin_amdgcn_mfma_f32_16x16x32_bf16(Y1[i], bhr, pr[1], 0, 0, 0);
            pz[0] = __builtin_amdgcn_mfma_f32_16x16x32_bf16(X0[i], bxz, pz[0], 0, 0, 0);
            pz[0] = __builtin_amdgcn_mfma_f32_16x16x32_bf16(Y0[i], bhz, pz[0], 0, 0, 0);
            pz[1] = __builtin_amdgcn_mfma_f32_16x16x32_bf16(X1[i], bxz, pz[1], 0, 0, 0);
            pz[1] = __builtin_amdgcn_mfma_f32_16x16x32_bf16(Y1[i], bhz, pz[1], 0, 0, 0);
            pxn[0] = __builtin_amdgcn_mfma_f32_16x16x32_bf16(X0[i], bxn, pxn[0], 0, 0, 0);
            pxn[1] = __builtin_amdgcn_mfma_f32_16x16x32_bf16(X1[i], bxn, pxn[1], 0, 0, 0);
            phn[0] = __builtin_amdgcn_mfma_f32_16x16x32_bf16(Y0[i], bhn, phn[0], 0, 0, 0);
            phn[1] = __builtin_amdgcn_mfma_f32_16x16x32_bf16(Y1[i], bhn, phn[1], 0, 0, 0);
          }
        }
      }
    }

    // cross-wave K-reduction of L1 partials
    #pragma unroll
    for (int r = 0; r < 3; ++r) {
      __syncthreads();
      if (wave >= 1 && s >= 1) {
        const int wi = wave - 1;
        #pragma unroll
        for (int j = 0; j < 8; ++j) {
          if (j % 3 == (wi + r) % 3) {
            const int gk = j >> 1, mt = j & 1;
            f32x4 v = (gk == 0) ? pr[mt] : (gk == 1) ? pz[mt] : (gk == 2) ? pxn[mt] : phn[mt];
            float* dstp = accS + j * 272;
            #pragma unroll
            for (int q = 0; q < 4; ++q) {
              int idx = (4 * l4 + q) * 17 + l15;
              if (r == 0) dstp[idx] = v[q];
              else dstp[idx] += v[q];
            }
          }
        }
      }
    }
    __syncthreads();
    if ((wave == 1 || wave == 2) && s >= 1) {
      const int mt = wave - 1;
      unsigned short* h1wr = h1b + (size_t)((s + 1) & 1) * 131072;
      #pragma unroll
      for (int q = 0; q < 4; ++q) {
        int idx = (4 * l4 + q) * 17 + l15;
        float rr = sigf(accS[(0 * 2 + mt) * 272 + idx] + b1r);
        float zz = sigf(accS[(1 * 2 + mt) * 272 + idx] + b1z);
        float nn = tanhs(accS[(2 * 2 + mt) * 272 + idx] + b1xn +
                         rr * (accS[(3 * 2 + mt) * 272 + idx] + b1hn));
        float hv = (1.f - zz) * nn + zz * h1m[q];
        h1m[q] = hv;
        int b = rowbase + mt * 16 + 4 * l4 + q;
        st_wt(h1wr + (size_t)b * 512 + c, f2bf(hv));
      }
    }

    // ---- step barrier: drain -> flag -> poll -> single-wave inv -> release ----
    asm volatile("s_waitcnt vmcnt(0)" ::: "memory");
    __syncthreads();
    if (tid == 0)
      __hip_atomic_store(&flags[member], s + 1, __ATOMIC_RELAXED, __HIP_MEMORY_SCOPE_AGENT);
    if (tid < 32) {
      while (__hip_atomic_load(&flags[tid], __ATOMIC_RELAXED, __HIP_MEMORY_SCOPE_AGENT) < s + 1) {
      }
    }
    if (wave == 0) __builtin_amdgcn_fence(__ATOMIC_ACQUIRE, "agent");
    __syncthreads();
  }

  // ================= dense head =================
  gbar(barall, 256);

  {
    const int mi = bid & 15, ni = bid >> 4;
    const unsigned short* A = h1b + 131072 + (size_t)(16 * mi) * 512;
    const int colb = 64 * ni + 16 * wave;
    f32x4 acc = z4;
    #pragma unroll 4
    for (int kc = 0; kc < 16; ++kc) {
      bf16x8 a = loadA(A, kc);
      bf16x8 bb = *(const bf16x8*)(Wd1b + (size_t)(colb + l15) * 512 + (kc << 5) + (l4 << 3));
      acc = __builtin_amdgcn_mfma_f32_16x16x32_bf16(a, bb, acc, 0, 0, 0);
    }
    #pragma unroll
    for (int q = 0; q < 4; ++q) {
      int row = 16 * mi + 4 * l4 + q, col = colb + l15;
      Y1[(size_t)row * 1024 + col] = acc[q] + bd1[col];
    }
  }
  gbar(barall, 256);

  {
    float* red = (float*)lds;
    for (int cc = 0; cc < 4; ++cc) {
      int col = bid * 4 + cc;
      float x = Y1[(size_t)tid * 1024 + col];
      red[tid] = x; __syncthreads();
      for (int st = 128; st > 0; st >>= 1) { if (tid < st) red[tid] += red[tid + st]; __syncthreads(); }
      float mean = red[0] * (1.f / 256.f); __syncthreads();
      float d = x - mean;
      red[tid] = d * d; __syncthreads();
      for (int st = 128; st > 0; st >>= 1) { if (tid < st) red[tid] += red[tid + st]; __syncthreads(); }
      float var = red[0] * (1.f / 256.f); __syncthreads();
      float xn = gam1[col] * d * rsqrtf(var + 1e-5f) + bet1[col];
      X1b[(size_t)tid * 1024 + col] = f2bf(fmaxf(xn, 0.f));
    }
  }
  gbar(barall, 256);

  {
    const int mi = bid & 15, ni = bid >> 4;
    if (wave < 2) {
      const unsigned short* A = X1b + (size_t)(16 * mi) * 1024;
      const int colb = 32 * ni + 16 * wave;
      f32x4 acc = z4;
      #pragma unroll 4
      for (int kc = 0; kc < 32; ++kc) {
        bf16x8 a = *(const bf16x8*)(A + (size_t)l15 * 1024 + (kc << 5) + (l4 << 3));
        bf16x8 bb = *(const bf16x8*)(Wd2b + (size_t)(colb + l15) * 1024 + (kc << 5) + (l4 << 3));
        acc = __builtin_amdgcn_mfma_f32_16x16x32_bf16(a, bb, acc, 0, 0, 0);
      }
      #pragma unroll
      for (int q = 0; q < 4; ++q) {
        int row = 16 * mi + 4 * l4 + q, col = colb + l15;
        Y2[(size_t)row * 512 + col] = acc[q] + bd2[col];
      }
    }
  }
  gbar(barall, 256);

  {
    float* red = (float*)lds;
    for (int cc = 0; cc < 2; ++cc) {
      int col = bid * 2 + cc;
      float x = Y2[(size_t)tid * 512 + col];
      red[tid] = x; __syncthreads();
      for (int st = 128; st > 0; st >>= 1) { if (tid < st) red[tid] += red[tid + st]; __syncthreads(); }
      float mean = red[0] * (1.f / 256.f); __syncthreads();
      float d = x - mean;
      red[tid] = d * d; __syncthreads();
      for (int st = 128; st > 0; st >>= 1) { if (tid < st) red[tid] += red[tid + st]; __syncthreads(); }
      float var = red[0] * (1.f / 256.f); __syncthreads();
      float xn = gam2[col] * d * rsqrtf(var + 1e-5f) + bet2[col];
      X2b[(size_t)tid * 512 + col] = f2bf(fmaxf(xn, 0.f));
    }
  }
  gbar(barall, 256);

  {
    const int b = bid;
    float xa = bf2f(X2b[(size_t)b * 512 + tid]);
    float xb2 = bf2f(X2b[(size_t)b * 512 + 256 + tid]);
    float* red = (float*)lds;
    for (int t = 0; t < 12; ++t) {
      float p = xa * Wm[t * 512 + tid] + xb2 * Wm[t * 512 + 256 + tid];
      red[tid] = p; __syncthreads();
      for (int st = 128; st > 0; st >>= 1) { if (tid < st) red[tid] += red[tid + st]; __syncthreads(); }
      if (tid == 0) out[b * 12 + t] = sigf(red[0] + bm[t]);
      __syncthreads();
    }
  }
}

// ---------------- host launcher ----------------
extern "C" void kernel_launch(void* const* d_in, const int* in_sizes, int n_in,
                              void* d_out, int out_size, void* d_ws, size_t ws_size,
                              hipStream_t stream) {
  const int* smiles = (const int*)d_in[0];
  const float* emb = (const float*)d_in[1];
  const float* Wih0 = (const float*)d_in[2];
  const float* Whh0 = (const float*)d_in[3];
  const float* bih0 = (const float*)d_in[4];
  const float* bhh0 = (const float*)d_in[5];
  const float* Wih1 = (const float*)d_in[6];
  const float* Whh1 = (const float*)d_in[7];
  const float* bih1 = (const float*)d_in[8];
  const float* bhh1 = (const float*)d_in[9];
  const float* Wd1 = (const float*)d_in[10];
  const float* bd1 = (const float*)d_in[11];
  const float* g1 = (const float*)d_in[12];
  const float* be1 = (const float*)d_in[13];
  const float* Wd2 = (const float*)d_in[14];
  const float* bd2 = (const float*)d_in[15];
  const float* g2 = (const float*)d_in[16];
  const float* be2 = (const float*)d_in[17];
  const float* We = (const float*)d_in[18];
  const float* be = (const float*)d_in[19];
  char* ws = (char*)d_ws;
  float* out = (float*)d_out;

  k_zero<<<256, 256, 0, stream>>>((uint4*)(ws + WS_H0B), 65536);
  k_zero<<<1, 256, 0, stream>>>((uint4*)(ws + WS_BAR), 256);
  k_cvt<<<768, 256, 0, stream>>>(Whh0, (unsigned short*)(ws + WS_WHH0B), 786432);
  k_cvt<<<768, 256, 0, stream>>>(Wih1, (unsigned short*)(ws + WS_WIH1B), 786432);
  k_cvt<<<768, 256, 0, stream>>>(Whh1, (unsigned short*)(ws + WS_WHH1B), 786432);
  k_cvt<<<512, 256, 0, stream>>>(Wd1, (unsigned short*)(ws + WS_WD1B), 524288);
  k_cvt<<<512, 256, 0, stream>>>(Wd2, (unsigned short*)(ws + WS_WD2B), 524288);
  k_table<<<128, 256, 0, stream>>>(emb, Wih0, bih0, (float*)(ws + WS_TABLE0));
  k_wm<<<24, 256, 0, stream>>>(We, be, (float*)(ws + WS_WM), (float*)(ws + WS_BM));

  const int LDS_BYTES = 156160;
  hipFuncSetAttribute((const void*)k_main, hipFuncAttributeMaxDynamicSharedMemorySize, LDS_BYTES);
  k_main<<<256, 256, LDS_BYTES, stream>>>(smiles, bhh0, bih1, bhh1, bd1, g1, be1,
                                          bd2, g2, be2, ws, out);
}